// Round 14
// baseline (14892.555 us; speedup 1.0000x reference)
//
#include <hip/hip_runtime.h>
#include <hip/hip_bf16.h>
#include <cstdint>

#define TT 2048
#define NPRED 512
#define NSTEP (TT + NPRED)   // 2560 phases; phase k: layer0(k) + layer1(k-1)

typedef _Float16 f16;
typedef __attribute__((ext_vector_type(8))) _Float16 f16x8;
typedef __attribute__((ext_vector_type(4))) float f32x4;

// ws layout (bytes) — identical to R12
#define WB0_OFF   0u          // f16 [16 slice][4 w][10 frag][64 lane][8] = 327680 elem
#define WB1_OFF   655360u     // f16 [16][4][16][64][8] = 524288 elem
#define BIAS0_OFF 1703936u    // f32 [256 j][4 q]
#define BIAS1_OFF 1708032u    // f32 [256][4]
#define HX0_OFF   1712128u    // f16 [2][256 b][256 j] = 262144 B
#define HX1_OFF   1974272u    // f16 [2][256][256]     = 262144 B
#define FLAG_OFF  2236416u    // uint [32][64]: counter g at [g*64] — one cache line per counter
#define PACC_OFF  2244608u    // f32 [2][16 slice][256 global batch] = 32768 B

static __device__ __forceinline__ float sigmoidf_(float x) {
    return 1.0f / (1.0f + __expf(-x));
}

// relaxed agent-scope accessors: per-instruction coherence, no cache flush
static __device__ __forceinline__ uint2 ld8u(const unsigned short* p) {
    unsigned long long v = __hip_atomic_load((const unsigned long long*)p,
                                             __ATOMIC_RELAXED, __HIP_MEMORY_SCOPE_AGENT);
    uint2 r; r.x = (unsigned)v; r.y = (unsigned)(v >> 32); return r;
}
static __device__ __forceinline__ float ld1a(const float* p) {
    unsigned v = __hip_atomic_load((const unsigned*)p,
                                   __ATOMIC_RELAXED, __HIP_MEMORY_SCOPE_AGENT);
    return __uint_as_float(v);
}
static __device__ __forceinline__ void st1a(float* p, float v) {
    __hip_atomic_store((unsigned*)p, __float_as_uint(v),
                       __ATOMIC_RELAXED, __HIP_MEMORY_SCOPE_AGENT);
}
static __device__ __forceinline__ void st4a(unsigned* p, unsigned v) {
    __hip_atomic_store(p, v, __ATOMIC_RELAXED, __HIP_MEMORY_SCOPE_AGENT);
}
static __device__ __forceinline__ unsigned short f16bits(float x) {
    union { f16 h; unsigned short u; } cv;
    cv.h = (f16)x;
    return cv.u;
}

// in-register 4x4 transpose across lane quads (regs = other axis).
// Before: lane a (within quad) holds M[a][0..3] in v0..v3. After: lane a holds M[0..3][a].
static __device__ __forceinline__ void xpose4(int lane, float& v0, float& v1, float& v2, float& v3) {
    { float x = (lane & 1) ? v0 : v1; x = __shfl_xor(x, 1); if (lane & 1) v0 = x; else v1 = x; }
    { float x = (lane & 1) ? v2 : v3; x = __shfl_xor(x, 1); if (lane & 1) v2 = x; else v3 = x; }
    { float x = (lane & 2) ? v0 : v2; x = __shfl_xor(x, 2); if (lane & 2) v0 = x; else v2 = x; }
    { float x = (lane & 2) ? v1 : v3; x = __shfl_xor(x, 2); if (lane & 2) v1 = x; else v3 = x; }
}

// ---------------- prep: pack weights as per-wave MFMA B-fragments (f16) ----------------
#define N0_ELEM 327680
#define N1_ELEM 524288

__global__ __launch_bounds__(256) void prep_kernel(
    const float* __restrict__ W_ih0, const float* __restrict__ W_hh0,
    const float* __restrict__ b_ih0, const float* __restrict__ b_hh0,
    const float* __restrict__ W_ih1, const float* __restrict__ W_hh1,
    const float* __restrict__ b_ih1, const float* __restrict__ b_hh1,
    f16* __restrict__ WB0, f16* __restrict__ WB1,
    float* __restrict__ bias0P, float* __restrict__ bias1P,
    unsigned int* __restrict__ flags, float* __restrict__ p_part)
{
    int idx = blockIdx.x * 256 + threadIdx.x;
    if (idx < N0_ELEM) {
        int e = idx & 7, l = (idx >> 3) & 63;
        int rest = idx >> 9;
        int fr = rest % 10, sw = rest / 10;
        int w = sw & 3, slice = sw >> 2;
        int q = l & 3, jj = (l & 15) >> 2;
        int row = q * 256 + slice * 16 + 4 * w + jj;
        int k = fr * 32 + (l >> 4) * 8 + e;
        float v = (k < 64) ? W_ih0[row * 64 + k] : W_hh0[row * 256 + (k - 64)];
        WB0[idx] = (f16)v;
    } else if (idx < N0_ELEM + N1_ELEM) {
        int i2 = idx - N0_ELEM;
        int e = i2 & 7, l = (i2 >> 3) & 63;
        int rest = i2 >> 9;
        int fr = rest & 15, sw = rest >> 4;
        int w = sw & 3, slice = sw >> 2;
        int q = l & 3, jj = (l & 15) >> 2;
        int row = q * 256 + slice * 16 + 4 * w + jj;
        int k = fr * 32 + (l >> 4) * 8 + e;
        float v = (k < 256) ? W_ih1[row * 256 + k] : W_hh1[row * 256 + (k - 256)];
        WB1[i2] = (f16)v;
    } else if (idx < N0_ELEM + N1_ELEM + 1024) {
        int r = idx - (N0_ELEM + N1_ELEM);
        int j = r >> 2, q = r & 3;
        bias0P[r] = b_ih0[q * 256 + j] + b_hh0[q * 256 + j];
    } else if (idx < N0_ELEM + N1_ELEM + 2048) {
        int r = idx - (N0_ELEM + N1_ELEM + 1024);
        int j = r >> 2, q = r & 3;
        bias1P[r] = b_ih1[q * 256 + j] + b_hh1[q * 256 + j];
    } else if (idx < N0_ELEM + N1_ELEM + 2048 + 2048) {
        flags[idx - (N0_ELEM + N1_ELEM + 2048)] = 0u;
    } else if (idx < N0_ELEM + N1_ELEM + 2048 + 2048 + 8192) {
        p_part[idx - (N0_ELEM + N1_ELEM + 2048 + 2048)] = 0.f;
    }
}

// ---------------- fused weight-stationary scan + AR: in-register gate updates ----------------
// grid 256 = 16 groups x 16 slices; blockIdx = slice*16 + g.
// MFMA C-layout: lane l, reg r = gate-row (w*16 + (l&15)) for batch (l>>4)*4+r.
// After xpose4: lane l holds all 4 gate components (regs=q) for
//   batch Bl=(l>>4)*4+(l&3), j ujl = w*4+((l&15)>>2).
// Publish + per-wave counter add (target 64*(k+1)) — no gbuf LDS round-trip.
__global__ __launch_bounds__(256) void fused_kernel(
    const float* __restrict__ input,
    const float* __restrict__ conv_w, const float* __restrict__ conv_b,
    const f16* __restrict__ WB0, const f16* __restrict__ WB1,
    const float* __restrict__ bias0P, const float* __restrict__ bias1P,
    const float* __restrict__ lin_w, const float* __restrict__ lin_b,
    unsigned short* hx0, unsigned short* hx1,
    unsigned int* flags, float* p_part,
    float* __restrict__ out)
{
    const int t = threadIdx.x;
    const int lane = t & 63, w = t >> 6;
    const int g = blockIdx.x & 15, slice = blockIdx.x >> 4;

    __shared__ __align__(16) f16 Ah[18 * 65 * 8];
    __shared__ float cw_s[64], cb_s[64];
    __shared__ float p_lds[16];
    __shared__ float p_part4[4][16];

    // B-fragments (weights) -> registers, resident for whole kernel
    f16x8 B0[10], B1[16];
    {
        const f16* p0 = WB0 + ((size_t)(slice * 4 + w) * 10 * 64 + lane) * 8;
        #pragma unroll
        for (int f = 0; f < 10; ++f) B0[f] = *(const f16x8*)(p0 + f * 512);
        const f16* p1 = WB1 + ((size_t)(slice * 4 + w) * 16 * 64 + lane) * 8;
        #pragma unroll
        for (int f = 0; f < 16; ++f) B1[f] = *(const f16x8*)(p1 + f * 512);
    }

    if (t < 64) { cw_s[t] = conv_w[t]; cb_s[t] = conv_b[t]; }

    // zero-init frags 2-17 (h0, h1 regions)
    #pragma unroll
    for (int i = 0; i < 4; ++i) {
        int c = t + 256 * i;
        int d = ((2 + (c >> 6)) * 65 + (c & 63)) * 8;
        f16x8 z = {};
        *(f16x8*)(Ah + d) = z;
    }

    // per-lane update roles (fixed for whole kernel)
    const int ujl = w * 4 + ((lane & 15) >> 2);     // j within slice
    const int jgl = slice * 16 + ujl;               // global j
    const int Bl  = (lane >> 4) * 4 + (lane & 3);   // batch within group
    const float4 bs0l = *(const float4*)(bias0P + 4 * jgl);
    const float4 bs1l = *(const float4*)(bias1P + 4 * jgl);
    const float lwl = lin_w[jgl];
    float c0 = 0.f, c1 = 0.f;
    const float linb = lin_b[0];

    // reader roles
    const int rb = t & 15;       // batch
    const int rest = t >> 4;     // oct index 0..15
    const int bg0 = g * 16;

    unsigned int* fl0 = flags + (size_t)g * 64;
    unsigned int* cnp = flags + (size_t)(16 + g) * 64;

    __syncthreads();

    //================= scan phases k = 0..TT-1 =================
    #pragma unroll 1
    for (int k = 0; k < TT; ++k) {
        // fill LDS: h0(k-1) -> frags 2-9, h1(k-2) -> frags 10-17, x(k) -> frags 0-1
        if (k >= 1) {
            const unsigned short* s0 = hx0 + (size_t)((k - 1) & 1) * 65536 + (size_t)(bg0 + rb) * 256;
            #pragma unroll
            for (int it = 0; it < 2; ++it) {
                int oct = rest + 16 * it;
                uint2 a = ld8u(s0 + oct * 8);
                uint2 b = ld8u(s0 + oct * 8 + 4);
                int d = ((2 + (oct >> 2)) * 65 + (rb + 16 * (oct & 3))) * 8;
                *(uint4*)(Ah + d) = make_uint4(a.x, a.y, b.x, b.y);
            }
        }
        if (k >= 2) {
            const unsigned short* s1 = hx1 + (size_t)((k - 1) & 1) * 65536 + (size_t)(bg0 + rb) * 256;
            #pragma unroll
            for (int it = 0; it < 2; ++it) {
                int oct = rest + 16 * it;
                uint2 a = ld8u(s1 + oct * 8);
                uint2 b = ld8u(s1 + oct * 8 + 4);
                int d = ((10 + (oct >> 2)) * 65 + (rb + 16 * (oct & 3))) * 8;
                *(uint4*)(Ah + d) = make_uint4(a.x, a.y, b.x, b.y);
            }
        }
        if (t < 128) {   // x(k): reshape semantics
            int rb2 = t & 15, xoct = t >> 4;
            int k0 = xoct * 8;
            const float* inprow = input + (size_t)(bg0 + rb2) * TT + ((k & 31) << 6);
            float cwv = cw_s[k >> 5], cbv = cb_s[k >> 5];
            f16x8 hv;
            #pragma unroll
            for (int e = 0; e < 8; ++e)
                hv[e] = (f16)fmaxf(inprow[k0 + e] * cwv + cbv, 0.f);
            int d = ((xoct >> 2) * 65 + (rb2 + 16 * (xoct & 3))) * 8;
            *(f16x8*)(Ah + d) = hv;
        }
        __syncthreads();   // Ah ready

        // MFMA both layers
        f32x4 a0 = {0.f, 0.f, 0.f, 0.f};
        #pragma unroll
        for (int f = 0; f < 10; ++f) {
            f16x8 a = *(const f16x8*)(Ah + (f * 65 + lane) * 8);
            a0 = __builtin_amdgcn_mfma_f32_16x16x32_f16(a, B0[f], a0, 0, 0, 0);
        }
        f32x4 a1 = {0.f, 0.f, 0.f, 0.f};
        if (k >= 1) {
            #pragma unroll
            for (int f = 0; f < 16; ++f) {
                f16x8 a = *(const f16x8*)(Ah + ((2 + f) * 65 + lane) * 8);
                a1 = __builtin_amdgcn_mfma_f32_16x16x32_f16(a, B1[f], a1, 0, 0, 0);
            }
        }

        // layer0 in-register update + publish
        {
            float v0 = a0[0], v1 = a0[1], v2 = a0[2], v3 = a0[3];
            xpose4(lane, v0, v1, v2, v3);
            float cn = sigmoidf_(v1 + bs0l.y) * c0 + sigmoidf_(v0 + bs0l.x) * tanhf(v2 + bs0l.z);
            float hn = sigmoidf_(v3 + bs0l.w) * tanhf(cn);
            c0 = cn;
            unsigned short hb = f16bits(hn);
            int oth = __shfl_xor((int)hb, 4);
            if (!(lane & 4)) {
                unsigned word = (unsigned)hb | ((unsigned)(oth & 0xffff) << 16);
                st4a((unsigned*)(hx0 + (size_t)(k & 1) * 65536 + (size_t)(bg0 + Bl) * 256 + (jgl & ~1)), word);
            }
        }
        if (k >= 1) {
            float v0 = a1[0], v1 = a1[1], v2 = a1[2], v3 = a1[3];
            xpose4(lane, v0, v1, v2, v3);
            float cn = sigmoidf_(v1 + bs1l.y) * c1 + sigmoidf_(v0 + bs1l.x) * tanhf(v2 + bs1l.z);
            float hn = sigmoidf_(v3 + bs1l.w) * tanhf(cn);
            c1 = cn;
            unsigned short hb = f16bits(hn);
            int oth = __shfl_xor((int)hb, 4);
            if (!(lane & 4)) {
                unsigned word = (unsigned)hb | ((unsigned)(oth & 0xffff) << 16);
                st4a((unsigned*)(hx1 + (size_t)(k & 1) * 65536 + (size_t)(bg0 + Bl) * 256 + (jgl & ~1)), word);
            }
        }

        // per-wave fence + counter add; t0 polls 64 adds per phase
        asm volatile("s_waitcnt vmcnt(0)" ::: "memory");
        if (lane == 0)
            __hip_atomic_fetch_add(fl0, 1u, __ATOMIC_RELAXED, __HIP_MEMORY_SCOPE_AGENT);
        if (t == 0) {
            unsigned tgt = 64u * (unsigned)(k + 1);
            while (__hip_atomic_load(fl0, __ATOMIC_RELAXED, __HIP_MEMORY_SCOPE_AGENT) < tgt)
                __builtin_amdgcn_s_sleep(1);
        }
        __syncthreads();
    }

    //================= AR phases k = TT..NSTEP-1 =================
    #pragma unroll 1
    for (int k = TT; k < NSTEP; ++k) {
        // fill LDS: h0(k-1) -> frags 2-9, h1(k-2) -> frags 10-17
        {
            const unsigned short* s0 = hx0 + (size_t)((k - 1) & 1) * 65536 + (size_t)(bg0 + rb) * 256;
            const unsigned short* s1 = hx1 + (size_t)((k - 1) & 1) * 65536 + (size_t)(bg0 + rb) * 256;
            #pragma unroll
            for (int it = 0; it < 2; ++it) {
                int oct = rest + 16 * it;
                uint2 a0v = ld8u(s0 + oct * 8);
                uint2 b0v = ld8u(s0 + oct * 8 + 4);
                int d = ((2 + (oct >> 2)) * 65 + (rb + 16 * (oct & 3))) * 8;
                *(uint4*)(Ah + d) = make_uint4(a0v.x, a0v.y, b0v.x, b0v.y);
                uint2 a1v = ld8u(s1 + oct * 8);
                uint2 b1v = ld8u(s1 + oct * 8 + 4);
                d = ((10 + (oct >> 2)) * 65 + (rb + 16 * (oct & 3))) * 8;
                *(uint4*)(Ah + d) = make_uint4(a1v.x, a1v.y, b1v.x, b1v.y);
            }
        }
        __syncthreads();   // Ah ready

        // layer1(k-1) MFMA + in-register update + publish + p-partials
        {
            f32x4 a1 = {0.f, 0.f, 0.f, 0.f};
            #pragma unroll
            for (int f = 0; f < 16; ++f) {
                f16x8 a = *(const f16x8*)(Ah + ((2 + f) * 65 + lane) * 8);
                a1 = __builtin_amdgcn_mfma_f32_16x16x32_f16(a, B1[f], a1, 0, 0, 0);
            }
            float v0 = a1[0], v1 = a1[1], v2 = a1[2], v3 = a1[3];
            xpose4(lane, v0, v1, v2, v3);
            float cn = sigmoidf_(v1 + bs1l.y) * c1 + sigmoidf_(v0 + bs1l.x) * tanhf(v2 + bs1l.z);
            float hn = sigmoidf_(v3 + bs1l.w) * tanhf(cn);
            c1 = cn;
            unsigned short hb = f16bits(hn);
            int oth = __shfl_xor((int)hb, 4);
            if (!(lane & 4)) {
                unsigned word = (unsigned)hb | ((unsigned)(oth & 0xffff) << 16);
                st4a((unsigned*)(hx1 + (size_t)(k & 1) * 65536 + (size_t)(bg0 + Bl) * 256 + (jgl & ~1)), word);
            }
            float pp = hn * lwl;
            pp += __shfl_xor(pp, 4);
            pp += __shfl_xor(pp, 8);
            if ((lane & 12) == 0) p_part4[w][Bl] = pp;
        }
        __syncthreads();   // p_part4 ready; h1 publishes drained

        if (t < 16) {
            float s4 = (p_part4[0][t] + p_part4[1][t]) + (p_part4[2][t] + p_part4[3][t]);
            st1a(p_part + (size_t)(k & 1) * 4096 + (size_t)slice * 256 + (bg0 + t), s4);
        }
        __syncthreads();   // p_part stores drained
        if (t == 0) {
            __hip_atomic_fetch_add(cnp, 1u, __ATOMIC_RELAXED, __HIP_MEMORY_SCOPE_AGENT);
            unsigned tgt = 16u * (unsigned)(k - TT + 1);
            while (__hip_atomic_load(cnp, __ATOMIC_RELAXED, __HIP_MEMORY_SCOPE_AGENT) < tgt)
                __builtin_amdgcn_s_sleep(1);
        }
        __syncthreads();

        // p = sum of 16 slice partials (deterministic order); out write
        if (t < 16) {
            const float* pb = p_part + (size_t)(k & 1) * 4096;
            float ps = 0.f;
            #pragma unroll
            for (int sl = 0; sl < 16; ++sl) ps += ld1a(pb + sl * 256 + bg0 + t);
            float p = ps + linb;
            p_lds[t] = p;
            if (slice == 0) out[(size_t)(bg0 + t) * NPRED + (k - TT)] = p;
        }
        if (k == NSTEP - 1) break;
        __syncthreads();   // p_lds visible

        // x(k) = relu(p*cw+cb)  (AR semantics, no reshape)
        if (t < 128) {
            int rb2 = t & 15, xoct = t >> 4;
            int k0 = xoct * 8;
            float p = p_lds[rb2];
            f16x8 hv;
            #pragma unroll
            for (int e = 0; e < 8; ++e)
                hv[e] = (f16)fmaxf(p * cw_s[k0 + e] + cb_s[k0 + e], 0.f);
            int d = ((xoct >> 2) * 65 + (rb2 + 16 * (xoct & 3))) * 8;
            *(f16x8*)(Ah + d) = hv;
        }
        __syncthreads();   // x ready (h0(k-1) frags 2-9 still resident)

        // layer0(k) MFMA + in-register update + publish
        {
            f32x4 a0 = {0.f, 0.f, 0.f, 0.f};
            #pragma unroll
            for (int f = 0; f < 10; ++f) {
                f16x8 a = *(const f16x8*)(Ah + (f * 65 + lane) * 8);
                a0 = __builtin_amdgcn_mfma_f32_16x16x32_f16(a, B0[f], a0, 0, 0, 0);
            }
            float v0 = a0[0], v1 = a0[1], v2 = a0[2], v3 = a0[3];
            xpose4(lane, v0, v1, v2, v3);
            float cn = sigmoidf_(v1 + bs0l.y) * c0 + sigmoidf_(v0 + bs0l.x) * tanhf(v2 + bs0l.z);
            float hn = sigmoidf_(v3 + bs0l.w) * tanhf(cn);
            c0 = cn;
            unsigned short hb = f16bits(hn);
            int oth = __shfl_xor((int)hb, 4);
            if (!(lane & 4)) {
                unsigned word = (unsigned)hb | ((unsigned)(oth & 0xffff) << 16);
                st4a((unsigned*)(hx0 + (size_t)(k & 1) * 65536 + (size_t)(bg0 + Bl) * 256 + (jgl & ~1)), word);
            }
        }
        asm volatile("s_waitcnt vmcnt(0)" ::: "memory");
        if (lane == 0)
            __hip_atomic_fetch_add(fl0, 1u, __ATOMIC_RELAXED, __HIP_MEMORY_SCOPE_AGENT);
        if (t == 0) {
            unsigned tgt = 64u * (unsigned)(k + 1);
            while (__hip_atomic_load(fl0, __ATOMIC_RELAXED, __HIP_MEMORY_SCOPE_AGENT) < tgt)
                __builtin_amdgcn_s_sleep(1);
        }
        __syncthreads();
    }
}

extern "C" void kernel_launch(void* const* d_in, const int* in_sizes, int n_in,
                              void* d_out, int out_size, void* d_ws, size_t ws_size,
                              hipStream_t stream) {
    const float* input  = (const float*)d_in[0];
    const float* conv_w = (const float*)d_in[1];
    const float* conv_b = (const float*)d_in[2];
    const float* W_ih0  = (const float*)d_in[3];
    const float* W_hh0  = (const float*)d_in[4];
    const float* b_ih0  = (const float*)d_in[5];
    const float* b_hh0  = (const float*)d_in[6];
    const float* W_ih1  = (const float*)d_in[7];
    const float* W_hh1  = (const float*)d_in[8];
    const float* b_ih1  = (const float*)d_in[9];
    const float* b_hh1  = (const float*)d_in[10];
    const float* lin_w  = (const float*)d_in[11];
    const float* lin_b  = (const float*)d_in[12];
    float* out = (float*)d_out;

    uint8_t* ws = (uint8_t*)d_ws;
    f16* WB0 = (f16*)(ws + WB0_OFF);
    f16* WB1 = (f16*)(ws + WB1_OFF);
    float* bias0P = (float*)(ws + BIAS0_OFF);
    float* bias1P = (float*)(ws + BIAS1_OFF);
    unsigned short* hx0 = (unsigned short*)(ws + HX0_OFF);
    unsigned short* hx1 = (unsigned short*)(ws + HX1_OFF);
    unsigned int* flags = (unsigned int*)(ws + FLAG_OFF);
    float* p_part = (float*)(ws + PACC_OFF);

    // 327680 + 524288 + 2048 + 2048 + 8192 = 864256 elems -> 3376 blocks of 256
    prep_kernel<<<3376, 256, 0, stream>>>(W_ih0, W_hh0, b_ih0, b_hh0,
                                          W_ih1, W_hh1, b_ih1, b_hh1,
                                          WB0, WB1, bias0P, bias1P, flags, p_part);

    fused_kernel<<<256, 256, 0, stream>>>(input, conv_w, conv_b,
                                          WB0, WB1, bias0P, bias1P,
                                          lin_w, lin_b, hx0, hx1, flags, p_part, out);
}

// Round 15
// 11437.309 us; speedup vs baseline: 1.3021x; 1.3021x over previous
//
#include <hip/hip_runtime.h>
#include <hip/hip_bf16.h>
#include <cstdint>

#define TT 2048
#define NPRED 512
#define NSTEP (TT + NPRED)   // 2560 phases; phase k: layer0(k) + layer1(k-1)

typedef _Float16 f16;
typedef __attribute__((ext_vector_type(8))) _Float16 f16x8;
typedef __attribute__((ext_vector_type(4))) float f32x4;
typedef unsigned long long u64;

// ws layout (bytes) — identical footprint to R12
#define WB0_OFF   0u          // f16 [16 slice][4 w][10 frag][64 lane][8] = 327680 elem
#define WB1_OFF   655360u     // f16 [16][4][16][64][8] = 524288 elem
#define BIAS0_OFF 1703936u    // f32 [256 j][4 q]
#define BIAS1_OFF 1708032u    // f32 [256][4]
#define HX0_OFF   1712128u    // u32 [2 buf][128 jp][256 gb] = 262144 B  (TRANSPOSED: jp-major)
#define HX1_OFF   1974272u    // u32 [2][128][256]           = 262144 B
#define FLAG_OFF  2236416u    // uint [32][64]: counter g at [g*64] — one cache line per counter
#define PACC_OFF  2244608u    // f32 [2][16 slice][256 global batch] = 32768 B

static __device__ __forceinline__ float sigmoidf_(float x) {
    return 1.0f / (1.0f + __expf(-x));
}

// relaxed agent-scope accessors: per-instruction coherence, no cache flush
static __device__ __forceinline__ u64 lda8w(const u64* p) {
    return __hip_atomic_load(p, __ATOMIC_RELAXED, __HIP_MEMORY_SCOPE_AGENT);
}
static __device__ __forceinline__ float ld1a(const float* p) {
    unsigned v = __hip_atomic_load((const unsigned*)p,
                                   __ATOMIC_RELAXED, __HIP_MEMORY_SCOPE_AGENT);
    return __uint_as_float(v);
}
static __device__ __forceinline__ void st1a(float* p, float v) {
    __hip_atomic_store((unsigned*)p, __float_as_uint(v),
                       __ATOMIC_RELAXED, __HIP_MEMORY_SCOPE_AGENT);
}
static __device__ __forceinline__ void st4a(unsigned* p, unsigned v) {
    __hip_atomic_store(p, v, __ATOMIC_RELAXED, __HIP_MEMORY_SCOPE_AGENT);
}
static __device__ __forceinline__ unsigned short f16bits(float x) {
    union { f16 h; unsigned short u; } cv;
    cv.h = (f16)x;
    return cv.u;
}

// ---------------- prep: pack weights as per-wave MFMA B-fragments (f16) ----------------
#define N0_ELEM 327680
#define N1_ELEM 524288

__global__ __launch_bounds__(256) void prep_kernel(
    const float* __restrict__ W_ih0, const float* __restrict__ W_hh0,
    const float* __restrict__ b_ih0, const float* __restrict__ b_hh0,
    const float* __restrict__ W_ih1, const float* __restrict__ W_hh1,
    const float* __restrict__ b_ih1, const float* __restrict__ b_hh1,
    f16* __restrict__ WB0, f16* __restrict__ WB1,
    float* __restrict__ bias0P, float* __restrict__ bias1P,
    unsigned int* __restrict__ flags, float* __restrict__ p_part)
{
    int idx = blockIdx.x * 256 + threadIdx.x;
    if (idx < N0_ELEM) {
        int e = idx & 7, l = (idx >> 3) & 63;
        int rest = idx >> 9;
        int fr = rest % 10, sw = rest / 10;
        int w = sw & 3, slice = sw >> 2;
        int q = l & 3, jj = (l & 15) >> 2;
        int row = q * 256 + slice * 16 + 4 * w + jj;
        int k = fr * 32 + (l >> 4) * 8 + e;
        float v = (k < 64) ? W_ih0[row * 64 + k] : W_hh0[row * 256 + (k - 64)];
        WB0[idx] = (f16)v;
    } else if (idx < N0_ELEM + N1_ELEM) {
        int i2 = idx - N0_ELEM;
        int e = i2 & 7, l = (i2 >> 3) & 63;
        int rest = i2 >> 9;
        int fr = rest & 15, sw = rest >> 4;
        int w = sw & 3, slice = sw >> 2;
        int q = l & 3, jj = (l & 15) >> 2;
        int row = q * 256 + slice * 16 + 4 * w + jj;
        int k = fr * 32 + (l >> 4) * 8 + e;
        float v = (k < 256) ? W_ih1[row * 256 + k] : W_hh1[row * 256 + (k - 256)];
        WB1[i2] = (f16)v;
    } else if (idx < N0_ELEM + N1_ELEM + 1024) {
        int r = idx - (N0_ELEM + N1_ELEM);
        int j = r >> 2, q = r & 3;
        bias0P[r] = b_ih0[q * 256 + j] + b_hh0[q * 256 + j];
    } else if (idx < N0_ELEM + N1_ELEM + 2048) {
        int r = idx - (N0_ELEM + N1_ELEM + 1024);
        int j = r >> 2, q = r & 3;
        bias1P[r] = b_ih1[q * 256 + j] + b_hh1[q * 256 + j];
    } else if (idx < N0_ELEM + N1_ELEM + 2048 + 2048) {
        flags[idx - (N0_ELEM + N1_ELEM + 2048)] = 0u;
    } else if (idx < N0_ELEM + N1_ELEM + 2048 + 2048 + 8192) {
        p_part[idx - (N0_ELEM + N1_ELEM + 2048 + 2048)] = 0.f;
    }
}

// ---------------- fused weight-stationary scan + AR (R12 structure, TRANSPOSED hx transport) ----------------
// grid 256 = 16 groups x 16 slices; blockIdx = slice*16 + g.
// Phase k: layer0(k) [frags 0-9] + layer1(k-1) [frags 2-17]; ONE barrier per scan phase.
// hx word layout: [buf][jp 0..127][gb 0..255], word = {f16 h[2jp] | f16 h[2jp+1]<<16}.
// Publisher: thread t<128 owns (jp_loc=t>>4, batch col=t&15) -> 16-lane 64B-coalesced row stores.
// Reader: 4 passes/layer, 8 lanes x 8B contiguous per jp-row -> 64B-coalesced reads.
__global__ __launch_bounds__(256) void fused_kernel(
    const float* __restrict__ input,
    const float* __restrict__ conv_w, const float* __restrict__ conv_b,
    const f16* __restrict__ WB0, const f16* __restrict__ WB1,
    const float* __restrict__ bias0P, const float* __restrict__ bias1P,
    const float* __restrict__ lin_w, const float* __restrict__ lin_b,
    unsigned* hx0w, unsigned* hx1w,
    unsigned int* flags, float* p_part,
    float* __restrict__ out)
{
    const int t = threadIdx.x;
    const int lane = t & 63, w = t >> 6;
    const int g = blockIdx.x & 15, slice = blockIdx.x >> 4;

    __shared__ __align__(16) f16 Ah[18 * 65 * 8];
    __shared__ __align__(16) float gbuf0[16 * 68 + 4];
    __shared__ __align__(16) float gbuf1[16 * 68 + 4];
    __shared__ float cw_s[64], cb_s[64];
    __shared__ float p_lds[16];
    __shared__ float p_part4[2][16];

    // B-fragments (weights) -> registers, resident for whole kernel
    f16x8 B0[10], B1[16];
    {
        const f16* p0 = WB0 + ((size_t)(slice * 4 + w) * 10 * 64 + lane) * 8;
        #pragma unroll
        for (int f = 0; f < 10; ++f) B0[f] = *(const f16x8*)(p0 + f * 512);
        const f16* p1 = WB1 + ((size_t)(slice * 4 + w) * 16 * 64 + lane) * 8;
        #pragma unroll
        for (int f = 0; f < 16; ++f) B1[f] = *(const f16x8*)(p1 + f * 512);
    }

    if (t < 64) { cw_s[t] = conv_w[t]; cb_s[t] = conv_b[t]; }

    // zero-init frags 2-17 (h0, h1 regions)
    #pragma unroll
    for (int i = 0; i < 4; ++i) {
        int c = t + 256 * i;
        int d = ((2 + (c >> 6)) * 65 + (c & 63)) * 8;
        f16x8 z = {};
        *(f16x8*)(Ah + d) = z;
    }

    // update role (t<128): owns j-pair (jga, jga+1) for batch (bg0+ucol)
    const int jploc = t >> 4;            // 0..7 (valid when t<128)
    const int ucol  = t & 15;
    const int jga   = slice * 16 + jploc * 2;
    float4 ba0 = make_float4(0.f,0.f,0.f,0.f), bb0 = ba0, ba1 = ba0, bb1 = ba0;
    float lwa = 0.f, lwb = 0.f;
    if (t < 128) {
        ba0 = *(const float4*)(bias0P + 4 * jga);
        bb0 = *(const float4*)(bias0P + 4 * jga + 4);
        ba1 = *(const float4*)(bias1P + 4 * jga);
        bb1 = *(const float4*)(bias1P + 4 * jga + 4);
        lwa = lin_w[jga];
        lwb = lin_w[jga + 1];
    }
    float c0a = 0.f, c0b = 0.f, c1a = 0.f, c1b = 0.f;
    const float linb = lin_b[0];
    const int bg0 = g * 16;

    unsigned int* fl0 = flags + (size_t)g * 64;
    unsigned int* cnp = flags + (size_t)(16 + g) * 64;

    __syncthreads();

    //================= scan phases k = 0..TT-1: ONE barrier each =================
    #pragma unroll 1
    for (int k = 0; k < TT; ++k) {
        // fill LDS from transposed hx: h0(k-1) -> frags 2-9, h1(k-2) -> frags 10-17
        if (k >= 1) {
            const unsigned* s0 = hx0w + (size_t)((k - 1) & 1) * 32768;
            #pragma unroll
            for (int p = 0; p < 4; ++p) {
                int row = p * 32 + (t >> 3);      // jp 0..127
                int cp  = t & 7;
                u64 v = lda8w((const u64*)(s0 + row * 256 + bg0 + 2 * cp));
                int f  = 2 + (row >> 4);
                int la = 2 * cp + 16 * ((row & 15) >> 2);
                int byte = (f * 65 + la) * 16 + 4 * (row & 3);
                *(unsigned*)((char*)Ah + byte)      = (unsigned)v;
                *(unsigned*)((char*)Ah + byte + 16) = (unsigned)(v >> 32);
            }
        }
        if (k >= 2) {
            const unsigned* s1 = hx1w + (size_t)((k - 1) & 1) * 32768;
            #pragma unroll
            for (int p = 0; p < 4; ++p) {
                int row = p * 32 + (t >> 3);
                int cp  = t & 7;
                u64 v = lda8w((const u64*)(s1 + row * 256 + bg0 + 2 * cp));
                int f  = 10 + (row >> 4);
                int la = 2 * cp + 16 * ((row & 15) >> 2);
                int byte = (f * 65 + la) * 16 + 4 * (row & 3);
                *(unsigned*)((char*)Ah + byte)      = (unsigned)v;
                *(unsigned*)((char*)Ah + byte + 16) = (unsigned)(v >> 32);
            }
        }
        if (t < 128) {   // x(k): reshape semantics
            int rb2 = t & 15, xoct = t >> 4;
            int k0 = xoct * 8;
            const float* inprow = input + (size_t)(bg0 + rb2) * TT + ((k & 31) << 6);
            float cwv = cw_s[k >> 5], cbv = cb_s[k >> 5];
            f16x8 hv;
            #pragma unroll
            for (int e = 0; e < 8; ++e)
                hv[e] = (f16)fmaxf(inprow[k0 + e] * cwv + cbv, 0.f);
            int d = ((xoct >> 2) * 65 + (rb2 + 16 * (xoct & 3))) * 8;
            *(f16x8*)(Ah + d) = hv;
        }
        __syncthreads();   // Ah ready

        // MFMA both layers off the same LDS state
        {
            f32x4 acc = {0.f, 0.f, 0.f, 0.f};
            #pragma unroll
            for (int f = 0; f < 10; ++f) {
                f16x8 a = *(const f16x8*)(Ah + (f * 65 + lane) * 8);
                acc = __builtin_amdgcn_mfma_f32_16x16x32_f16(a, B0[f], acc, 0, 0, 0);
            }
            int rr = w * 16 + (lane & 15);
            int bb = (lane >> 4) * 4;
            #pragma unroll
            for (int qq = 0; qq < 4; ++qq) gbuf0[(bb + qq) * 68 + rr] = acc[qq];
        }
        if (k >= 1) {
            f32x4 acc = {0.f, 0.f, 0.f, 0.f};
            #pragma unroll
            for (int f = 0; f < 16; ++f) {
                f16x8 a = *(const f16x8*)(Ah + ((2 + f) * 65 + lane) * 8);
                acc = __builtin_amdgcn_mfma_f32_16x16x32_f16(a, B1[f], acc, 0, 0, 0);
            }
            int rr = w * 16 + (lane & 15);
            int bb = (lane >> 4) * 4;
            #pragma unroll
            for (int qq = 0; qq < 4; ++qq) gbuf1[(bb + qq) * 68 + rr] = acc[qq];
        }
        __syncthreads();   // gbuf ready

        // updates + coalesced transposed publish (t<128: one u32 word per thread)
        if (t < 128) {
            const float* gp = gbuf0 + ucol * 68 + jploc * 8;
            float4 g0 = *(const float4*)(gp);
            float4 g1 = *(const float4*)(gp + 4);
            float cna = sigmoidf_(g0.y + ba0.y) * c0a + sigmoidf_(g0.x + ba0.x) * tanhf(g0.z + ba0.z);
            float hna = sigmoidf_(g0.w + ba0.w) * tanhf(cna);
            c0a = cna;
            float cnb = sigmoidf_(g1.y + bb0.y) * c0b + sigmoidf_(g1.x + bb0.x) * tanhf(g1.z + bb0.z);
            float hnb = sigmoidf_(g1.w + bb0.w) * tanhf(cnb);
            c0b = cnb;
            unsigned word = (unsigned)f16bits(hna) | ((unsigned)f16bits(hnb) << 16);
            st4a(hx0w + (size_t)(k & 1) * 32768 + (size_t)(slice * 8 + jploc) * 256 + (bg0 + ucol), word);
            if (k >= 1) {
                const float* hp = gbuf1 + ucol * 68 + jploc * 8;
                float4 h0v = *(const float4*)(hp);
                float4 h1v = *(const float4*)(hp + 4);
                float cka = sigmoidf_(h0v.y + ba1.y) * c1a + sigmoidf_(h0v.x + ba1.x) * tanhf(h0v.z + ba1.z);
                float hka = sigmoidf_(h0v.w + ba1.w) * tanhf(cka);
                c1a = cka;
                float ckb = sigmoidf_(h1v.y + bb1.y) * c1b + sigmoidf_(h1v.x + bb1.x) * tanhf(h1v.z + bb1.z);
                float hkb = sigmoidf_(h1v.w + bb1.w) * tanhf(ckb);
                c1b = ckb;
                unsigned wrd = (unsigned)f16bits(hka) | ((unsigned)f16bits(hkb) << 16);
                st4a(hx1w + (size_t)(k & 1) * 32768 + (size_t)(slice * 8 + jploc) * 256 + (bg0 + ucol), wrd);
            }
        }
        __syncthreads();   // drains stores (vmcnt0 before s_barrier)
        if (t == 0) {
            __hip_atomic_fetch_add(fl0, 1u, __ATOMIC_RELAXED, __HIP_MEMORY_SCOPE_AGENT);
            unsigned tgt = 16u * (unsigned)(k + 1);
            while (__hip_atomic_load(fl0, __ATOMIC_RELAXED, __HIP_MEMORY_SCOPE_AGENT) < tgt)
                __builtin_amdgcn_s_sleep(1);
        }
        __syncthreads();
    }

    //================= AR phases k = TT..NSTEP-1: layer1(k-1) -> p -> layer0(k) =================
    #pragma unroll 1
    for (int k = TT; k < NSTEP; ++k) {
        // fill LDS: h0(k-1) -> frags 2-9, h1(k-2) -> frags 10-17
        {
            const unsigned* s0 = hx0w + (size_t)((k - 1) & 1) * 32768;
            const unsigned* s1 = hx1w + (size_t)((k - 1) & 1) * 32768;
            #pragma unroll
            for (int p = 0; p < 4; ++p) {
                int row = p * 32 + (t >> 3);
                int cp  = t & 7;
                u64 v0 = lda8w((const u64*)(s0 + row * 256 + bg0 + 2 * cp));
                int la = 2 * cp + 16 * ((row & 15) >> 2);
                int byte0 = ((2 + (row >> 4)) * 65 + la) * 16 + 4 * (row & 3);
                *(unsigned*)((char*)Ah + byte0)      = (unsigned)v0;
                *(unsigned*)((char*)Ah + byte0 + 16) = (unsigned)(v0 >> 32);
                u64 v1 = lda8w((const u64*)(s1 + row * 256 + bg0 + 2 * cp));
                int byte1 = ((10 + (row >> 4)) * 65 + la) * 16 + 4 * (row & 3);
                *(unsigned*)((char*)Ah + byte1)      = (unsigned)v1;
                *(unsigned*)((char*)Ah + byte1 + 16) = (unsigned)(v1 >> 32);
            }
        }
        __syncthreads();   // Ah ready

        // layer1(k-1)
        {
            f32x4 acc = {0.f, 0.f, 0.f, 0.f};
            #pragma unroll
            for (int f = 0; f < 16; ++f) {
                f16x8 a = *(const f16x8*)(Ah + ((2 + f) * 65 + lane) * 8);
                acc = __builtin_amdgcn_mfma_f32_16x16x32_f16(a, B1[f], acc, 0, 0, 0);
            }
            int rr = w * 16 + (lane & 15);
            int bb = (lane >> 4) * 4;
            #pragma unroll
            for (int qq = 0; qq < 4; ++qq) gbuf1[(bb + qq) * 68 + rr] = acc[qq];
        }
        __syncthreads();   // gbuf1 ready

        // h1 update + transposed publish + p-partials (per-wave reduce)
        if (t < 128) {
            const float* hp = gbuf1 + ucol * 68 + jploc * 8;
            float4 h0v = *(const float4*)(hp);
            float4 h1v = *(const float4*)(hp + 4);
            float cka = sigmoidf_(h0v.y + ba1.y) * c1a + sigmoidf_(h0v.x + ba1.x) * tanhf(h0v.z + ba1.z);
            float hka = sigmoidf_(h0v.w + ba1.w) * tanhf(cka);
            c1a = cka;
            float ckb = sigmoidf_(h1v.y + bb1.y) * c1b + sigmoidf_(h1v.x + bb1.x) * tanhf(h1v.z + bb1.z);
            float hkb = sigmoidf_(h1v.w + bb1.w) * tanhf(ckb);
            c1b = ckb;
            unsigned wrd = (unsigned)f16bits(hka) | ((unsigned)f16bits(hkb) << 16);
            st4a(hx1w + (size_t)(k & 1) * 32768 + (size_t)(slice * 8 + jploc) * 256 + (bg0 + ucol), wrd);
            float pp = hka * lwa + hkb * lwb;
            pp += __shfl_xor(pp, 16);
            pp += __shfl_xor(pp, 32);
            if ((lane & 48) == 0) p_part4[w][ucol] = pp;   // lane<16 of waves 0,1
        }
        __syncthreads();   // p_part4 ready
        if (t < 16) {
            float s4 = p_part4[0][t] + p_part4[1][t];
            st1a(p_part + (size_t)(k & 1) * 4096 + (size_t)slice * 256 + (bg0 + t), s4);
        }
        __syncthreads();   // drain p_part + hx1 stores
        if (t == 0) {
            __hip_atomic_fetch_add(cnp, 1u, __ATOMIC_RELAXED, __HIP_MEMORY_SCOPE_AGENT);
            unsigned tgt = 16u * (unsigned)(k - TT + 1);
            while (__hip_atomic_load(cnp, __ATOMIC_RELAXED, __HIP_MEMORY_SCOPE_AGENT) < tgt)
                __builtin_amdgcn_s_sleep(1);
        }
        __syncthreads();

        // p = sum of 16 slice partials (deterministic order); out write
        if (t < 16) {
            const float* pb = p_part + (size_t)(k & 1) * 4096;
            float ps = 0.f;
            #pragma unroll
            for (int sl = 0; sl < 16; ++sl) ps += ld1a(pb + sl * 256 + bg0 + t);
            float p = ps + linb;
            p_lds[t] = p;
            if (slice == 0) out[(size_t)(bg0 + t) * NPRED + (k - TT)] = p;
        }
        if (k == NSTEP - 1) break;
        __syncthreads();   // p_lds visible

        // x(k) = relu(p*cw+cb)  (AR semantics, no reshape)
        if (t < 128) {
            int rb2 = t & 15, xoct = t >> 4;
            int k0 = xoct * 8;
            float p = p_lds[rb2];
            f16x8 hv;
            #pragma unroll
            for (int e = 0; e < 8; ++e)
                hv[e] = (f16)fmaxf(p * cw_s[k0 + e] + cb_s[k0 + e], 0.f);
            int d = ((xoct >> 2) * 65 + (rb2 + 16 * (xoct & 3))) * 8;
            *(f16x8*)(Ah + d) = hv;
        }
        __syncthreads();   // x ready (h0(k-1) frags 2-9 still resident)

        // layer0(k)
        {
            f32x4 acc = {0.f, 0.f, 0.f, 0.f};
            #pragma unroll
            for (int f = 0; f < 10; ++f) {
                f16x8 a = *(const f16x8*)(Ah + (f * 65 + lane) * 8);
                acc = __builtin_amdgcn_mfma_f32_16x16x32_f16(a, B0[f], acc, 0, 0, 0);
            }
            int rr = w * 16 + (lane & 15);
            int bb = (lane >> 4) * 4;
            #pragma unroll
            for (int qq = 0; qq < 4; ++qq) gbuf0[(bb + qq) * 68 + rr] = acc[qq];
        }
        __syncthreads();   // gbuf0 ready
        if (t < 128) {
            const float* gp = gbuf0 + ucol * 68 + jploc * 8;
            float4 g0 = *(const float4*)(gp);
            float4 g1 = *(const float4*)(gp + 4);
            float cna = sigmoidf_(g0.y + ba0.y) * c0a + sigmoidf_(g0.x + ba0.x) * tanhf(g0.z + ba0.z);
            float hna = sigmoidf_(g0.w + ba0.w) * tanhf(cna);
            c0a = cna;
            float cnb = sigmoidf_(g1.y + bb0.y) * c0b + sigmoidf_(g1.x + bb0.x) * tanhf(g1.z + bb0.z);
            float hnb = sigmoidf_(g1.w + bb0.w) * tanhf(cnb);
            c0b = cnb;
            unsigned word = (unsigned)f16bits(hna) | ((unsigned)f16bits(hnb) << 16);
            st4a(hx0w + (size_t)(k & 1) * 32768 + (size_t)(slice * 8 + jploc) * 256 + (bg0 + ucol), word);
        }
        __syncthreads();   // drain stores
        if (t == 0) {
            __hip_atomic_fetch_add(fl0, 1u, __ATOMIC_RELAXED, __HIP_MEMORY_SCOPE_AGENT);
            unsigned tgt = 16u * (unsigned)(k + 1);
            while (__hip_atomic_load(fl0, __ATOMIC_RELAXED, __HIP_MEMORY_SCOPE_AGENT) < tgt)
                __builtin_amdgcn_s_sleep(1);
        }
        __syncthreads();
    }
}

extern "C" void kernel_launch(void* const* d_in, const int* in_sizes, int n_in,
                              void* d_out, int out_size, void* d_ws, size_t ws_size,
                              hipStream_t stream) {
    const float* input  = (const float*)d_in[0];
    const float* conv_w = (const float*)d_in[1];
    const float* conv_b = (const float*)d_in[2];
    const float* W_ih0  = (const float*)d_in[3];
    const float* W_hh0  = (const float*)d_in[4];
    const float* b_ih0  = (const float*)d_in[5];
    const float* b_hh0  = (const float*)d_in[6];
    const float* W_ih1  = (const float*)d_in[7];
    const float* W_hh1  = (const float*)d_in[8];
    const float* b_ih1  = (const float*)d_in[9];
    const float* b_hh1  = (const float*)d_in[10];
    const float* lin_w  = (const float*)d_in[11];
    const float* lin_b  = (const float*)d_in[12];
    float* out = (float*)d_out;

    uint8_t* ws = (uint8_t*)d_ws;
    f16* WB0 = (f16*)(ws + WB0_OFF);
    f16* WB1 = (f16*)(ws + WB1_OFF);
    float* bias0P = (float*)(ws + BIAS0_OFF);
    float* bias1P = (float*)(ws + BIAS1_OFF);
    unsigned* hx0w = (unsigned*)(ws + HX0_OFF);
    unsigned* hx1w = (unsigned*)(ws + HX1_OFF);
    unsigned int* flags = (unsigned int*)(ws + FLAG_OFF);
    float* p_part = (float*)(ws + PACC_OFF);

    // 327680 + 524288 + 2048 + 2048 + 8192 = 864256 elems -> 3376 blocks of 256
    prep_kernel<<<3376, 256, 0, stream>>>(W_ih0, W_hh0, b_ih0, b_hh0,
                                          W_ih1, W_hh1, b_ih1, b_hh1,
                                          WB0, WB1, bias0P, bias1P, flags, p_part);

    fused_kernel<<<256, 256, 0, stream>>>(input, conv_w, conv_b,
                                          WB0, WB1, bias0P, bias1P,
                                          lin_w, lin_b, hx0w, hx1w, flags, p_part, out);
}

// Round 17
// 9232.901 us; speedup vs baseline: 1.6130x; 1.2388x over previous
//
#include <hip/hip_runtime.h>
#include <hip/hip_bf16.h>
#include <cstdint>

#define TT 2048
#define NPRED 512
#define NSTEP (TT + NPRED)   // 2560 phases; phase k: layer0(k) + layer1(k-1)

typedef _Float16 f16;
typedef __attribute__((ext_vector_type(8))) _Float16 f16x8;
typedef __attribute__((ext_vector_type(4))) float f32x4;

// ws layout (bytes)
#define WB0_OFF   0u          // f16 [16 slice][4 w][10 frag][64 lane][8] = 327680 elem
#define WB1_OFF   655360u     // f16 [16][4][16][64][8] = 524288 elem
#define BIAS0_OFF 1703936u    // f32 [256 j][4 q]
#define BIAS1_OFF 1708032u    // f32 [256][4]
#define HX0_OFF   1712128u    // f16 [2][256 b][256 j] = 262144 B   (h published as f16)
#define HX1_OFF   1974272u    // f16 [2][256][256]     = 262144 B
#define FLAG_OFF  2236416u    // uint [32][64]: counter g at [g*64] — one cache line per counter
#define PACC_OFF  2244608u    // f32 [2][16 slice][256 global batch] = 32768 B

static __device__ __forceinline__ float sigmoidf_(float x) {
    return 1.0f / (1.0f + __expf(-x));
}

// relaxed agent-scope accessors: per-instruction coherence (bypass stale L2, no cache flush)
static __device__ __forceinline__ uint2 ld8u(const unsigned short* p) {
    unsigned long long v = __hip_atomic_load((const unsigned long long*)p,
                                             __ATOMIC_RELAXED, __HIP_MEMORY_SCOPE_AGENT);
    uint2 r; r.x = (unsigned)v; r.y = (unsigned)(v >> 32); return r;
}
static __device__ __forceinline__ float ld1a(const float* p) {
    unsigned v = __hip_atomic_load((const unsigned*)p,
                                   __ATOMIC_RELAXED, __HIP_MEMORY_SCOPE_AGENT);
    return __uint_as_float(v);
}
static __device__ __forceinline__ void st1a(float* p, float v) {
    __hip_atomic_store((unsigned*)p, __float_as_uint(v),
                       __ATOMIC_RELAXED, __HIP_MEMORY_SCOPE_AGENT);
}
static __device__ __forceinline__ void st4a(unsigned* p, unsigned v) {
    __hip_atomic_store(p, v, __ATOMIC_RELAXED, __HIP_MEMORY_SCOPE_AGENT);
}
static __device__ __forceinline__ unsigned short f16bits(float x) {
    union { f16 h; unsigned short u; } cv;
    cv.h = (f16)x;
    return cv.u;
}

// ---------------- prep: pack weights as per-wave MFMA B-fragments (f16) ----------------
#define N0_ELEM 327680
#define N1_ELEM 524288

__global__ __launch_bounds__(256) void prep_kernel(
    const float* __restrict__ W_ih0, const float* __restrict__ W_hh0,
    const float* __restrict__ b_ih0, const float* __restrict__ b_hh0,
    const float* __restrict__ W_ih1, const float* __restrict__ W_hh1,
    const float* __restrict__ b_ih1, const float* __restrict__ b_hh1,
    f16* __restrict__ WB0, f16* __restrict__ WB1,
    float* __restrict__ bias0P, float* __restrict__ bias1P,
    unsigned int* __restrict__ flags, float* __restrict__ p_part)
{
    int idx = blockIdx.x * 256 + threadIdx.x;
    if (idx < N0_ELEM) {
        int e = idx & 7, l = (idx >> 3) & 63;
        int rest = idx >> 9;
        int fr = rest % 10, sw = rest / 10;
        int w = sw & 3, slice = sw >> 2;
        int q = l & 3, jj = (l & 15) >> 2;
        int row = q * 256 + slice * 16 + 4 * w + jj;
        int k = fr * 32 + (l >> 4) * 8 + e;
        float v = (k < 64) ? W_ih0[row * 64 + k] : W_hh0[row * 256 + (k - 64)];
        WB0[idx] = (f16)v;
    } else if (idx < N0_ELEM + N1_ELEM) {
        int i2 = idx - N0_ELEM;
        int e = i2 & 7, l = (i2 >> 3) & 63;
        int rest = i2 >> 9;
        int fr = rest & 15, sw = rest >> 4;
        int w = sw & 3, slice = sw >> 2;
        int q = l & 3, jj = (l & 15) >> 2;
        int row = q * 256 + slice * 16 + 4 * w + jj;
        int k = fr * 32 + (l >> 4) * 8 + e;
        float v = (k < 256) ? W_ih1[row * 256 + k] : W_hh1[row * 256 + (k - 256)];
        WB1[i2] = (f16)v;
    } else if (idx < N0_ELEM + N1_ELEM + 1024) {
        int r = idx - (N0_ELEM + N1_ELEM);
        int j = r >> 2, q = r & 3;
        bias0P[r] = b_ih0[q * 256 + j] + b_hh0[q * 256 + j];
    } else if (idx < N0_ELEM + N1_ELEM + 2048) {
        int r = idx - (N0_ELEM + N1_ELEM + 1024);
        int j = r >> 2, q = r & 3;
        bias1P[r] = b_ih1[q * 256 + j] + b_hh1[q * 256 + j];
    } else if (idx < N0_ELEM + N1_ELEM + 2048 + 2048) {
        flags[idx - (N0_ELEM + N1_ELEM + 2048)] = 0u;
    } else if (idx < N0_ELEM + N1_ELEM + 2048 + 2048 + 8192) {
        p_part[idx - (N0_ELEM + N1_ELEM + 2048 + 2048)] = 0.f;
    }
}

// ---------------- fused weight-stationary scan + AR (f16 A-path, single plane) ----------------
// grid 256 = 16 groups x 16 slices; blockIdx = slice*16 + g.
// Phase k: layer0(k) [frags 0-9] + layer1(k-1) [frags 2-17]; ONE barrier per scan phase.
// A frags: [0-1: x(k) | 2-9: h0(k-1) | 10-17: h1(k-2)].  h published as f16 pairs.
__global__ __launch_bounds__(256) void fused_kernel(
    const float* __restrict__ input,
    const float* __restrict__ conv_w, const float* __restrict__ conv_b,
    const f16* __restrict__ WB0, const f16* __restrict__ WB1,
    const float* __restrict__ bias0P, const float* __restrict__ bias1P,
    const float* __restrict__ lin_w, const float* __restrict__ lin_b,
    unsigned short* hx0, unsigned short* hx1,
    unsigned int* flags, float* p_part,
    float* __restrict__ out)
{
    const int t = threadIdx.x;
    const int lane = t & 63, w = t >> 6;
    const int g = blockIdx.x & 15, slice = blockIdx.x >> 4;

    __shared__ __align__(16) f16 Ah[18 * 65 * 8];
    __shared__ __align__(16) float gbuf0[16 * 68 + 4];
    __shared__ __align__(16) float gbuf1[16 * 68 + 4];
    __shared__ float cw_s[64], cb_s[64], lw_s[256];
    __shared__ float p_lds[16];

    // B-fragments (weights) -> registers, resident for whole kernel
    f16x8 B0[10], B1[16];
    {
        const f16* p0 = WB0 + ((size_t)(slice * 4 + w) * 10 * 64 + lane) * 8;
        #pragma unroll
        for (int f = 0; f < 10; ++f) B0[f] = *(const f16x8*)(p0 + f * 512);
        const f16* p1 = WB1 + ((size_t)(slice * 4 + w) * 16 * 64 + lane) * 8;
        #pragma unroll
        for (int f = 0; f < 16; ++f) B1[f] = *(const f16x8*)(p1 + f * 512);
    }

    if (t < 64) { cw_s[t] = conv_w[t]; cb_s[t] = conv_b[t]; }
    lw_s[t] = lin_w[t];

    // zero-init frags 2-17 (h0, h1 regions)
    #pragma unroll
    for (int i = 0; i < 4; ++i) {
        int c = t + 256 * i;
        int d = ((2 + (c >> 6)) * 65 + (c & 63)) * 8;
        f16x8 z = {};
        *(f16x8*)(Ah + d) = z;
    }

    // h-update role
    const int ub = t >> 4, uj = t & 15;
    const int jg = slice * 16 + uj;
    const float4 bs0 = *(const float4*)(bias0P + 4 * jg);
    const float4 bs1 = *(const float4*)(bias1P + 4 * jg);
    float c0 = 0.f, c1 = 0.f;
    const float linb = lin_b[0];

    // reader roles
    const int rb = t & 15;       // batch
    const int rest = t >> 4;     // oct index 0..15
    const int bg0 = g * 16;

    unsigned int* fl0 = flags + (size_t)g * 64;
    unsigned int* cnp = flags + (size_t)(16 + g) * 64;

    __syncthreads();

    //================= scan phases k = 0..TT-1: ONE barrier each =================
    #pragma unroll 1
    for (int k = 0; k < TT; ++k) {
        // fill LDS: h0(k-1) -> frags 2-9, h1(k-2) -> frags 10-17, x(k) -> frags 0-1
        if (k >= 1) {
            const unsigned short* s0 = hx0 + (size_t)((k - 1) & 1) * 65536 + (size_t)(bg0 + rb) * 256;
            #pragma unroll
            for (int it = 0; it < 2; ++it) {
                int oct = rest + 16 * it;
                uint2 a = ld8u(s0 + oct * 8);
                uint2 b = ld8u(s0 + oct * 8 + 4);
                int d = ((2 + (oct >> 2)) * 65 + (rb + 16 * (oct & 3))) * 8;
                *(uint4*)(Ah + d) = make_uint4(a.x, a.y, b.x, b.y);
            }
        }
        if (k >= 2) {
            const unsigned short* s1 = hx1 + (size_t)((k - 1) & 1) * 65536 + (size_t)(bg0 + rb) * 256;
            #pragma unroll
            for (int it = 0; it < 2; ++it) {
                int oct = rest + 16 * it;
                uint2 a = ld8u(s1 + oct * 8);
                uint2 b = ld8u(s1 + oct * 8 + 4);
                int d = ((10 + (oct >> 2)) * 65 + (rb + 16 * (oct & 3))) * 8;
                *(uint4*)(Ah + d) = make_uint4(a.x, a.y, b.x, b.y);
            }
        }
        if (t < 128) {   // x(k): reshape semantics
            int rb2 = t & 15, xoct = t >> 4;   // 0..7
            int k0 = xoct * 8;
            const float* inprow = input + (size_t)(bg0 + rb2) * TT + ((k & 31) << 6);
            float cwv = cw_s[k >> 5], cbv = cb_s[k >> 5];
            f16x8 hv;
            #pragma unroll
            for (int e = 0; e < 8; ++e)
                hv[e] = (f16)fmaxf(inprow[k0 + e] * cwv + cbv, 0.f);
            int d = ((xoct >> 2) * 65 + (rb2 + 16 * (xoct & 3))) * 8;
            *(f16x8*)(Ah + d) = hv;
        }
        __syncthreads();   // Ah ready

        // both MFMA stages off the same LDS state (single f16 plane)
        {
            f32x4 acc = {0.f, 0.f, 0.f, 0.f};
            #pragma unroll
            for (int f = 0; f < 10; ++f) {
                f16x8 a = *(const f16x8*)(Ah + (f * 65 + lane) * 8);
                acc = __builtin_amdgcn_mfma_f32_16x16x32_f16(a, B0[f], acc, 0, 0, 0);
            }
            int rr = w * 16 + (lane & 15);
            int bb = (lane >> 4) * 4;
            #pragma unroll
            for (int qq = 0; qq < 4; ++qq) gbuf0[(bb + qq) * 68 + rr] = acc[qq];
        }
        if (k >= 1) {
            f32x4 acc = {0.f, 0.f, 0.f, 0.f};
            #pragma unroll
            for (int f = 0; f < 16; ++f) {
                f16x8 a = *(const f16x8*)(Ah + ((2 + f) * 65 + lane) * 8);
                acc = __builtin_amdgcn_mfma_f32_16x16x32_f16(a, B1[f], acc, 0, 0, 0);
            }
            int rr = w * 16 + (lane & 15);
            int bb = (lane >> 4) * 4;
            #pragma unroll
            for (int qq = 0; qq < 4; ++qq) gbuf1[(bb + qq) * 68 + rr] = acc[qq];
        }
        __syncthreads();

        // updates + f16-pair publish
        {
            float4 gv = *(const float4*)(gbuf0 + ub * 68 + uj * 4);
            float gi = gv.x + bs0.x, gf = gv.y + bs0.y, gg = gv.z + bs0.z, go = gv.w + bs0.w;
            float cn = sigmoidf_(gf) * c0 + sigmoidf_(gi) * tanhf(gg);
            float hn = sigmoidf_(go) * tanhf(cn);
            c0 = cn;
            unsigned short hb = f16bits(hn);
            int oth = __shfl_xor((int)hb, 1);
            if (!(uj & 1)) {
                unsigned word = (unsigned)hb | ((unsigned)(oth & 0xffff) << 16);
                st4a((unsigned*)(hx0 + (size_t)(k & 1) * 65536 + (size_t)(bg0 + ub) * 256 + jg), word);
            }
        }
        if (k >= 1) {
            float4 gv = *(const float4*)(gbuf1 + ub * 68 + uj * 4);
            float gi = gv.x + bs1.x, gf = gv.y + bs1.y, gg = gv.z + bs1.z, go = gv.w + bs1.w;
            float cn = sigmoidf_(gf) * c1 + sigmoidf_(gi) * tanhf(gg);
            float hn = sigmoidf_(go) * tanhf(cn);
            c1 = cn;
            unsigned short hb = f16bits(hn);
            int oth = __shfl_xor((int)hb, 1);
            if (!(uj & 1)) {
                unsigned word = (unsigned)hb | ((unsigned)(oth & 0xffff) << 16);
                st4a((unsigned*)(hx1 + (size_t)(k & 1) * 65536 + (size_t)(bg0 + ub) * 256 + jg), word);
            }
        }
        __syncthreads();   // drains stores (vmcnt0 before s_barrier)
        if (t == 0) {
            __hip_atomic_fetch_add(fl0, 1u, __ATOMIC_RELAXED, __HIP_MEMORY_SCOPE_AGENT);
            unsigned tgt = 16u * (unsigned)(k + 1);
            while (__hip_atomic_load(fl0, __ATOMIC_RELAXED, __HIP_MEMORY_SCOPE_AGENT) < tgt)
                __builtin_amdgcn_s_sleep(1);
        }
        __syncthreads();
    }

    //================= AR phases k = TT..NSTEP-1: layer1(k-1) -> p -> layer0(k) =================
    #pragma unroll 1
    for (int k = TT; k < NSTEP; ++k) {
        // fill LDS: h0(k-1) -> frags 2-9, h1(k-2) -> frags 10-17
        {
            const unsigned short* s0 = hx0 + (size_t)((k - 1) & 1) * 65536 + (size_t)(bg0 + rb) * 256;
            const unsigned short* s1 = hx1 + (size_t)((k - 1) & 1) * 65536 + (size_t)(bg0 + rb) * 256;
            #pragma unroll
            for (int it = 0; it < 2; ++it) {
                int oct = rest + 16 * it;
                uint2 a0 = ld8u(s0 + oct * 8);
                uint2 b0 = ld8u(s0 + oct * 8 + 4);
                int d = ((2 + (oct >> 2)) * 65 + (rb + 16 * (oct & 3))) * 8;
                *(uint4*)(Ah + d) = make_uint4(a0.x, a0.y, b0.x, b0.y);
                uint2 a1 = ld8u(s1 + oct * 8);
                uint2 b1 = ld8u(s1 + oct * 8 + 4);
                d = ((10 + (oct >> 2)) * 65 + (rb + 16 * (oct & 3))) * 8;
                *(uint4*)(Ah + d) = make_uint4(a1.x, a1.y, b1.x, b1.y);
            }
        }
        __syncthreads();

        // layer1(k-1)
        {
            f32x4 acc = {0.f, 0.f, 0.f, 0.f};
            #pragma unroll
            for (int f = 0; f < 16; ++f) {
                f16x8 a = *(const f16x8*)(Ah + ((2 + f) * 65 + lane) * 8);
                acc = __builtin_amdgcn_mfma_f32_16x16x32_f16(a, B1[f], acc, 0, 0, 0);
            }
            int rr = w * 16 + (lane & 15);
            int bb = (lane >> 4) * 4;
            #pragma unroll
            for (int qq = 0; qq < 4; ++qq) gbuf1[(bb + qq) * 68 + rr] = acc[qq];
        }
        __syncthreads();

        // h1 update + f16 publish + deterministic p-partials (f32 hn)
        {
            float4 gv = *(const float4*)(gbuf1 + ub * 68 + uj * 4);
            float gi = gv.x + bs1.x, gf = gv.y + bs1.y, gg = gv.z + bs1.z, go = gv.w + bs1.w;
            float cn = sigmoidf_(gf) * c1 + sigmoidf_(gi) * tanhf(gg);
            float hn = sigmoidf_(go) * tanhf(cn);
            c1 = cn;
            unsigned short hb = f16bits(hn);
            int oth = __shfl_xor((int)hb, 1);
            if (!(uj & 1)) {
                unsigned word = (unsigned)hb | ((unsigned)(oth & 0xffff) << 16);
                st4a((unsigned*)(hx1 + (size_t)(k & 1) * 65536 + (size_t)(bg0 + ub) * 256 + jg), word);
            }
            float pp = hn * lw_s[jg];
            pp += __shfl_xor(pp, 1);
            pp += __shfl_xor(pp, 2);
            pp += __shfl_xor(pp, 4);
            pp += __shfl_xor(pp, 8);
            if (uj == 0)
                st1a(p_part + (size_t)(k & 1) * 4096 + (size_t)slice * 256 + (bg0 + ub), pp);
        }
        __syncthreads();   // drain stores
        if (t == 0) {
            __hip_atomic_fetch_add(cnp, 1u, __ATOMIC_RELAXED, __HIP_MEMORY_SCOPE_AGENT);
            unsigned tgt = 16u * (unsigned)(k - TT + 1);
            while (__hip_atomic_load(cnp, __ATOMIC_RELAXED, __HIP_MEMORY_SCOPE_AGENT) < tgt)
                __builtin_amdgcn_s_sleep(1);
        }
        __syncthreads();

        // p = sum of 16 slice partials for THIS group's batches ; out write
        if (t < 16) {
            const float* pb = p_part + (size_t)(k & 1) * 4096;
            float ps = 0.f;
            #pragma unroll
            for (int sl = 0; sl < 16; ++sl) ps += ld1a(pb + sl * 256 + bg0 + t);
            float p = ps + linb;
            p_lds[t] = p;
            if (slice == 0) out[(size_t)(bg0 + t) * NPRED + (k - TT)] = p;
        }
        if (k == NSTEP - 1) break;
        __syncthreads();   // p_lds visible

        // x(k) = relu(p*cw+cb)  (AR semantics, no reshape)
        if (t < 128) {
            int rb2 = t & 15, xoct = t >> 4;
            int k0 = xoct * 8;
            float p = p_lds[rb2];
            f16x8 hv;
            #pragma unroll
            for (int e = 0; e < 8; ++e)
                hv[e] = (f16)fmaxf(p * cw_s[k0 + e] + cb_s[k0 + e], 0.f);
            int d = ((xoct >> 2) * 65 + (rb2 + 16 * (xoct & 3))) * 8;
            *(f16x8*)(Ah + d) = hv;
        }
        __syncthreads();

        // layer0(k)
        {
            f32x4 acc = {0.f, 0.f, 0.f, 0.f};
            #pragma unroll
            for (int f = 0; f < 10; ++f) {
                f16x8 a = *(const f16x8*)(Ah + (f * 65 + lane) * 8);
                acc = __builtin_amdgcn_mfma_f32_16x16x32_f16(a, B0[f], acc, 0, 0, 0);
            }
            int rr = w * 16 + (lane & 15);
            int bb = (lane >> 4) * 4;
            #pragma unroll
            for (int qq = 0; qq < 4; ++qq) gbuf0[(bb + qq) * 68 + rr] = acc[qq];
        }
        __syncthreads();
        {
            float4 gv = *(const float4*)(gbuf0 + ub * 68 + uj * 4);
            float gi = gv.x + bs0.x, gf = gv.y + bs0.y, gg = gv.z + bs0.z, go = gv.w + bs0.w;
            float cn = sigmoidf_(gf) * c0 + sigmoidf_(gi) * tanhf(gg);
            float hn = sigmoidf_(go) * tanhf(cn);
            c0 = cn;
            unsigned short hb = f16bits(hn);
            int oth = __shfl_xor((int)hb, 1);
            if (!(uj & 1)) {
                unsigned word = (unsigned)hb | ((unsigned)(oth & 0xffff) << 16);
                st4a((unsigned*)(hx0 + (size_t)(k & 1) * 65536 + (size_t)(bg0 + ub) * 256 + jg), word);
            }
        }
        __syncthreads();   // drain stores
        if (t == 0) {
            __hip_atomic_fetch_add(fl0, 1u, __ATOMIC_RELAXED, __HIP_MEMORY_SCOPE_AGENT);
            unsigned tgt = 16u * (unsigned)(k + 1);
            while (__hip_atomic_load(fl0, __ATOMIC_RELAXED, __HIP_MEMORY_SCOPE_AGENT) < tgt)
                __builtin_amdgcn_s_sleep(1);
        }
        __syncthreads();
    }
}

extern "C" void kernel_launch(void* const* d_in, const int* in_sizes, int n_in,
                              void* d_out, int out_size, void* d_ws, size_t ws_size,
                              hipStream_t stream) {
    const float* input  = (const float*)d_in[0];
    const float* conv_w = (const float*)d_in[1];
    const float* conv_b = (const float*)d_in[2];
    const float* W_ih0  = (const float*)d_in[3];
    const float* W_hh0  = (const float*)d_in[4];
    const float* b_ih0  = (const float*)d_in[5];
    const float* b_hh0  = (const float*)d_in[6];
    const float* W_ih1  = (const float*)d_in[7];
    const float* W_hh1  = (const float*)d_in[8];
    const float* b_ih1  = (const float*)d_in[9];
    const float* b_hh1  = (const float*)d_in[10];
    const float* lin_w  = (const float*)d_in[11];
    const float* lin_b  = (const float*)d_in[12];
    float* out = (float*)d_out;

    uint8_t* ws = (uint8_t*)d_ws;
    f16* WB0 = (f16*)(ws + WB0_OFF);
    f16* WB1 = (f16*)(ws + WB1_OFF);
    float* bias0P = (float*)(ws + BIAS0_OFF);
    float* bias1P = (float*)(ws + BIAS1_OFF);
    unsigned short* hx0 = (unsigned short*)(ws + HX0_OFF);
    unsigned short* hx1 = (unsigned short*)(ws + HX1_OFF);
    unsigned int* flags = (unsigned int*)(ws + FLAG_OFF);
    float* p_part = (float*)(ws + PACC_OFF);

    // 327680 + 524288 + 2048 + 2048 + 8192 = 864256 elems -> 3376 blocks of 256
    prep_kernel<<<3376, 256, 0, stream>>>(W_ih0, W_hh0, b_ih0, b_hh0,
                                          W_ih1, W_hh1, b_ih1, b_hh1,
                                          WB0, WB1, bias0P, bias1P, flags, p_part);

    fused_kernel<<<256, 256, 0, stream>>>(input, conv_w, conv_b,
                                          WB0, WB1, bias0P, bias1P,
                                          lin_w, lin_b, hx0, hx1, flags, p_part, out);
}